// Round 9
// baseline (247.239 us; speedup 1.0000x reference)
//
#include <hip/hip_runtime.h>
#include <hip/hip_bf16.h>

#define M_DIM 8192   // 4 * 2048 rows of x
#define N_DIM 8192   // out_features
#define K_DIM 2048   // in_features (= bytes per int8 row)

#define BK 64                 // int8 elems per K-tile
#define NT (K_DIM / BK)       // 32 K-tiles
#define SLOT_BYTES 16384      // A-only slot: [256 rows][64 B]

typedef float f32x4 __attribute__((ext_vector_type(4)));
typedef int   i32x4 __attribute__((ext_vector_type(4)));
typedef unsigned int u32;
typedef u32 u32x2 __attribute__((ext_vector_type(2)));
typedef u32 u32x4 __attribute__((ext_vector_type(4)));

// ---------- helpers ----------

__device__ __forceinline__ void gload16(const unsigned char* g, char* l) {
    __builtin_amdgcn_global_load_lds(
        (const __attribute__((address_space(1))) u32*)g,
        (__attribute__((address_space(3))) u32*)l, 16, 0, 0);
}

__device__ __forceinline__ u32 pack4(int a, int b, int c, int d) {
    return (u32)(a & 255) | ((u32)(b & 255) << 8) |
           ((u32)(c & 255) << 16) | ((u32)(d & 255) << 24);
}

// ---------- prepass: per-row symmetric int8 quantization of x ----------

__global__ void __launch_bounds__(256) quant_x_k(const float* __restrict__ x,
                                                 unsigned char* __restrict__ xq,
                                                 float* __restrict__ sx) {
    const int row = blockIdx.x;           // 8192 rows
    const int t = threadIdx.x;            // 256 thr, 8 elems each
    const float* xr = x + (size_t)row * K_DIM;
    f32x4 v0 = *((const f32x4*)xr + t * 2);
    f32x4 v1 = *((const f32x4*)xr + t * 2 + 1);
    float m = fabsf(v0[0]);
    m = fmaxf(m, fabsf(v0[1])); m = fmaxf(m, fabsf(v0[2])); m = fmaxf(m, fabsf(v0[3]));
    m = fmaxf(m, fabsf(v1[0])); m = fmaxf(m, fabsf(v1[1]));
    m = fmaxf(m, fabsf(v1[2])); m = fmaxf(m, fabsf(v1[3]));
#pragma unroll
    for (int off = 32; off >= 1; off >>= 1)
        m = fmaxf(m, __shfl_xor(m, off, 64));
    __shared__ float wmax[4];
    if ((t & 63) == 0) wmax[t >> 6] = m;
    __syncthreads();
    m = fmaxf(fmaxf(wmax[0], wmax[1]), fmaxf(wmax[2], wmax[3]));
    m = fmaxf(m, 1e-20f);
    const float rs = 127.0f / m;
    const int q0 = (int)rintf(v0[0] * rs), q1 = (int)rintf(v0[1] * rs);
    const int q2 = (int)rintf(v0[2] * rs), q3 = (int)rintf(v0[3] * rs);
    const int q4 = (int)rintf(v1[0] * rs), q5 = (int)rintf(v1[1] * rs);
    const int q6 = (int)rintf(v1[2] * rs), q7 = (int)rintf(v1[3] * rs);
    u32x2 o;
    o[0] = pack4(q0, q1, q2, q3);
    o[1] = pack4(q4, q5, q6, q7);
    *((u32x2*)(xq + (size_t)row * K_DIM) + t) = o;
    if (t == 0) sx[row] = m / 127.0f;
}

// ---------- prepass: int32 (harness int8-as-int32) -> packed int8 ----------

__global__ void __launch_bounds__(256) cvt_w_k(const int* __restrict__ w,
                                               unsigned char* __restrict__ wq, int n16) {
    const int stride = gridDim.x * blockDim.x;
    for (int i = blockIdx.x * blockDim.x + threadIdx.x; i < n16; i += stride) {
        const i32x4* p = (const i32x4*)w + (size_t)i * 4;
        i32x4 a = p[0], b = p[1], c = p[2], d = p[3];
        u32x4 o;
        o[0] = pack4(a[0], a[1], a[2], a[3]);
        o[1] = pack4(b[0], b[1], b[2], b[3]);
        o[2] = pack4(c[0], c[1], c[2], c[3]);
        o[3] = pack4(d[0], d[1], d[2], d[3]);
        *((u32x4*)wq + i) = o;
    }
}

// ---------- main GEMM: int8 x int8 -> i32, fp32 epilogue ----------
// r7/r8 skeleton with B TAKEN OUT OF LDS: A-only 16KB slots (4-deep pipeline,
// chunk-XOR swizzle, 0 conflicts); B fragments load global->VGPR directly into
// the bf0/bf1 double buffer (2x reuse hits L1; panels L2-resident). Ledger:
// 6 loads/body = {2 A-stage, 4 B-reg}; steady VM(6) completes {A(tk+2), B(tk)}.

__global__ void __launch_bounds__(512, 2)
gemm_i8(const unsigned char* __restrict__ Aq, const unsigned char* __restrict__ Bq,
        const float* __restrict__ sx, const float* __restrict__ sw,
        const float* __restrict__ bias, float* __restrict__ C) {
    extern __shared__ __align__(16) char ldsb[];

    // XCD-bijective swizzle (1024 blocks % 8 == 0)
    const int bid = blockIdx.x;
    const int swz = (bid & 7) * 128 + (bid >> 3);
    const int rowBase = (swz >> 5) * 256;
    const int colBase = (swz & 31) * 256;

    const int t = threadIdx.x;       // 0..511
    const int l = t & 63;
    const int w = t >> 6;
    const int wm = w >> 2;           // 0..1  (128-row half)
    const int wn = w & 3;            // 0..3  (64-col quarter)
    const int fr = l & 15;
    const int s4 = l >> 4;           // k-group (16 int8 = 16 B)

    // A staging: thread t -> row t>>2 (0..127) of each half, phys chunk t&3;
    // source k-offset pre-swizzled: logical chunk = phys ^ ((row>>1)&3)
    const int sr = t >> 2;
    const int sk = (((t & 3) ^ ((sr >> 1) & 3)) * 16);
    const unsigned char* gA0 = Aq + (size_t)(rowBase + sr) * K_DIM + sk;
    const unsigned char* gA1 = Aq + (size_t)(rowBase + 128 + sr) * K_DIM + sk;

#define STAGE_A(tk) do { \
        char* _b = ldsb + ((tk) & 3) * SLOT_BYTES; \
        const int _k = (tk) * BK; \
        gload16(gA0 + _k, _b + t * 16); \
        gload16(gA1 + _k, _b + 8192 + t * 16); \
    } while (0)

    // B fragment global base: row = colBase + wn*64 + ni*16 + fr, col byte s4*16
    const unsigned char* gBf = Bq + (size_t)(colBase + wn * 64 + fr) * K_DIM + s4 * 16;

#define BLOAD(dst, tk) do { \
        const unsigned char* _g = gBf + (size_t)(tk) * BK; \
        _Pragma("unroll") \
        for (int ni = 0; ni < 4; ++ni) \
            dst[ni] = *(const i32x4*)(_g + (size_t)ni * 16 * K_DIM); \
    } while (0)

    // A fragment read offsets within slot: key (row>>1)&3 == (fr>>1)&3
    const int pc = ((s4 ^ ((fr >> 1) & 3)) * 16);
    int aoff[8];
#pragma unroll
    for (int mi = 0; mi < 8; ++mi)
        aoff[mi] = (wm * 128 + mi * 16 + fr) * 64 + pc;

    i32x4 acc[8][4] = {};
    i32x4 afC[8], bf0[4], bf1[4];

#define SB    __builtin_amdgcn_sched_barrier(0)
#define BAR   __builtin_amdgcn_s_barrier()
#define P1    __builtin_amdgcn_s_setprio(1)
#define P0    __builtin_amdgcn_s_setprio(0)
#define LGKM0 asm volatile("s_waitcnt lgkmcnt(0)" ::: "memory")
#define VM6   asm volatile("s_waitcnt vmcnt(6)" ::: "memory")
#define VM4   asm volatile("s_waitcnt vmcnt(4)" ::: "memory")
#define VM2   asm volatile("s_waitcnt vmcnt(2)" ::: "memory")
#define VM0   asm volatile("s_waitcnt vmcnt(0)" ::: "memory")

#define READS_A(tk) do { \
        const char* _s = ldsb + ((tk) & 3) * SLOT_BYTES; \
        _Pragma("unroll") \
        for (int mi = 0; mi < 8; ++mi) afC[mi] = *(const i32x4*)(_s + aoff[mi]); \
    } while (0)

    // interleaved compute: per mi, 4 MFMAs consume afC[mi], then afC[mi] is
    // re-read from next tile's slot (WAR keeps order; LDS overlaps MFMA).
#define MFMA_ILV(BREG, NTK) do { P1; \
        const char* _n = ldsb + ((NTK) & 3) * SLOT_BYTES; \
        _Pragma("unroll") \
        for (int mi = 0; mi < 8; ++mi) { \
            _Pragma("unroll") \
            for (int ni = 0; ni < 4; ++ni) \
                acc[mi][ni] = __builtin_amdgcn_mfma_i32_16x16x64_i8( \
                    afC[mi], BREG[ni], acc[mi][ni], 0, 0, 0); \
            afC[mi] = *(const i32x4*)(_n + aoff[mi]); \
        } \
        P0; } while (0)

#define MFMA_ALL(BREG) do { P1; \
        _Pragma("unroll") \
        for (int mi = 0; mi < 8; ++mi) \
            _Pragma("unroll") \
            for (int ni = 0; ni < 4; ++ni) \
                acc[mi][ni] = __builtin_amdgcn_mfma_i32_16x16x64_i8( \
                    afC[mi], BREG[ni], acc[mi][ni], 0, 0, 0); \
        P0; } while (0)

#define BODY(TK, BCUR, BNXT) do { \
        STAGE_A((TK) + 3); \
        BLOAD(BNXT, (TK) + 1); \
        VM6; LGKM0; SB; BAR; SB; \
        MFMA_ILV(BCUR, (TK) + 1); \
    } while (0)

    // prologue: issue order A0, A1, B0, A2 -> VM(2) completes {A0, A1, B0}
    STAGE_A(0); STAGE_A(1);
    BLOAD(bf0, 0);
    STAGE_A(2);
    VM2; SB; BAR; SB;
    READS_A(0);

    // bodies 0..28: body tk stages A(tk+3), loads B(tk+1); VM(6) completes
    // {A(tk+2), B(tk)}; BAR publishes A(tk+2); ILV reads slot tk+1.
#pragma unroll 1
    for (int tk = 0; tk < NT - 4; tk += 2) {
        BODY(tk, bf0, bf1);
        BODY(tk + 1, bf1, bf0);
    }
    BODY(28, bf0, bf1);       // stages A(31), loads B(29)
    // body 29: no A-stage; queue {A31, B29, B30} -> VM(4) completes {A31, B29}
    BLOAD(bf0, 30);
    VM4; LGKM0; SB; BAR; SB;
    MFMA_ILV(bf1, 30);
    // body 30: queue {B30, B31} -> VM(4) completes B30
    BLOAD(bf1, 31);
    VM4; LGKM0; SB; BAR; SB;
    MFMA_ILV(bf0, 31);
    // body 31: final tile, all operands in regs
    VM0; LGKM0; SB;
    MFMA_ALL(bf1);

#undef BODY
#undef MFMA_ALL
#undef MFMA_ILV
#undef READS_A
#undef BLOAD
#undef STAGE_A

    // epilogue: C/D layout col=lane&15, row=(lane>>4)*4+reg (dtype-independent)
    // out = acc_i32 * sx[row] * sw[col] + bias[col]   (fp32, exact dequant)
#pragma unroll
    for (int ni = 0; ni < 4; ++ni) {
        const int col = colBase + wn * 64 + ni * 16 + fr;
        const float swc = sw[col];
        const float bz = bias[col];
#pragma unroll
        for (int mi = 0; mi < 8; ++mi) {
            const int rb = rowBase + wm * 128 + mi * 16 + s4 * 4;
            i32x4 a = acc[mi][ni];
#pragma unroll
            for (int r = 0; r < 4; ++r)
                C[(size_t)(rb + r) * N_DIM + col] =
                    (float)a[r] * (sx[rb + r] * swc) + bz;
        }
    }
}

// ---------- correctness fallback if workspace too small (should not trigger) ----------

typedef int i32x4_t __attribute__((ext_vector_type(4)));
__global__ void __launch_bounds__(256) naive_k(const float* __restrict__ x,
                                               const int* __restrict__ w,
                                               const float* __restrict__ scale,
                                               const float* __restrict__ bias,
                                               float* __restrict__ out) {
    __shared__ float xs[K_DIM];
    const int m = blockIdx.x >> 5;
    const int n = ((blockIdx.x & 31) << 8) + threadIdx.x;
    for (int i = threadIdx.x; i < K_DIM; i += 256) xs[i] = x[(size_t)m * K_DIM + i];
    __syncthreads();
    const int* wr = w + (size_t)n * K_DIM;
    float acc = 0.f;
    for (int k = 0; k < K_DIM; k += 4) {
        i32x4_t v = *(const i32x4_t*)(wr + k);
        acc += xs[k]     * (float)v[0];
        acc += xs[k + 1] * (float)v[1];
        acc += xs[k + 2] * (float)v[2];
        acc += xs[k + 3] * (float)v[3];
    }
    out[(size_t)m * N_DIM + n] = acc * scale[n] + bias[n];
}

// ---------- launch ----------

extern "C" void kernel_launch(void* const* d_in, const int* in_sizes, int n_in,
                              void* d_out, int out_size, void* d_ws, size_t ws_size,
                              hipStream_t stream) {
    const float* x     = (const float*)d_in[0];
    const int*   w8    = (const int*)d_in[1];   // int8 values stored as int32
    const float* sw    = (const float*)d_in[2];
    const float* bias  = (const float*)d_in[3];
    float*       out   = (float*)d_out;

    const size_t xq_bytes = (size_t)M_DIM * K_DIM;          // 16 MB
    const size_t wq_bytes = (size_t)N_DIM * K_DIM;          // 16 MB
    const size_t need = xq_bytes + wq_bytes + (size_t)M_DIM * sizeof(float);
    if (ws_size >= need) {
        unsigned char* xq = (unsigned char*)d_ws;
        unsigned char* wq = xq + xq_bytes;
        float* sx = (float*)(wq + wq_bytes);
        hipFuncSetAttribute((const void*)gemm_i8,
                            hipFuncAttributeMaxDynamicSharedMemorySize, 65536);
        quant_x_k<<<M_DIM, 256, 0, stream>>>(x, xq, sx);
        cvt_w_k<<<2048, 256, 0, stream>>>(w8, wq, N_DIM * K_DIM / 16);
        gemm_i8<<<dim3((M_DIM / 256) * (N_DIM / 256)), 512, 65536, stream>>>(
            xq, wq, sx, sw, bias, out);
    } else {
        naive_k<<<(M_DIM * (N_DIM / 256)), 256, 0, stream>>>(x, w8, sw, bias, out);
    }
}

// Round 10
// 245.053 us; speedup vs baseline: 1.0089x; 1.0089x over previous
//
#include <hip/hip_runtime.h>
#include <hip/hip_bf16.h>

#define M_DIM 8192   // 4 * 2048 rows of x
#define N_DIM 8192   // out_features
#define K_DIM 2048   // in_features (= bytes per int8 row)

#define BK 64                 // int8 elems per K-tile
#define NT (K_DIM / BK)       // 32 K-tiles
#define SLOT_BYTES 24576      // A[128][64B] 8KB + B[256][64B] 16KB

typedef float f32x4 __attribute__((ext_vector_type(4)));
typedef int   i32x4 __attribute__((ext_vector_type(4)));
typedef unsigned int u32;
typedef u32 u32x2 __attribute__((ext_vector_type(2)));
typedef u32 u32x4 __attribute__((ext_vector_type(4)));

// ---------- helpers ----------

__device__ __forceinline__ void gload16(const unsigned char* g, char* l) {
    __builtin_amdgcn_global_load_lds(
        (const __attribute__((address_space(1))) u32*)g,
        (__attribute__((address_space(3))) u32*)l, 16, 0, 0);
}

__device__ __forceinline__ u32 pack4(int a, int b, int c, int d) {
    return (u32)(a & 255) | ((u32)(b & 255) << 8) |
           ((u32)(c & 255) << 16) | ((u32)(d & 255) << 24);
}

// ---------- prepass: per-row symmetric int8 quantization of x ----------

__global__ void __launch_bounds__(256) quant_x_k(const float* __restrict__ x,
                                                 unsigned char* __restrict__ xq,
                                                 float* __restrict__ sx) {
    const int row = blockIdx.x;           // 8192 rows
    const int t = threadIdx.x;            // 256 thr, 8 elems each
    const float* xr = x + (size_t)row * K_DIM;
    f32x4 v0 = *((const f32x4*)xr + t * 2);
    f32x4 v1 = *((const f32x4*)xr + t * 2 + 1);
    float m = fabsf(v0[0]);
    m = fmaxf(m, fabsf(v0[1])); m = fmaxf(m, fabsf(v0[2])); m = fmaxf(m, fabsf(v0[3]));
    m = fmaxf(m, fabsf(v1[0])); m = fmaxf(m, fabsf(v1[1]));
    m = fmaxf(m, fabsf(v1[2])); m = fmaxf(m, fabsf(v1[3]));
#pragma unroll
    for (int off = 32; off >= 1; off >>= 1)
        m = fmaxf(m, __shfl_xor(m, off, 64));
    __shared__ float wmax[4];
    if ((t & 63) == 0) wmax[t >> 6] = m;
    __syncthreads();
    m = fmaxf(fmaxf(wmax[0], wmax[1]), fmaxf(wmax[2], wmax[3]));
    m = fmaxf(m, 1e-20f);
    const float rs = 127.0f / m;
    const int q0 = (int)rintf(v0[0] * rs), q1 = (int)rintf(v0[1] * rs);
    const int q2 = (int)rintf(v0[2] * rs), q3 = (int)rintf(v0[3] * rs);
    const int q4 = (int)rintf(v1[0] * rs), q5 = (int)rintf(v1[1] * rs);
    const int q6 = (int)rintf(v1[2] * rs), q7 = (int)rintf(v1[3] * rs);
    u32x2 o;
    o[0] = pack4(q0, q1, q2, q3);
    o[1] = pack4(q4, q5, q6, q7);
    *((u32x2*)(xq + (size_t)row * K_DIM) + t) = o;
    if (t == 0) sx[row] = m / 127.0f;
}

// ---------- prepass: int32 (harness int8-as-int32) -> packed int8 ----------

__global__ void __launch_bounds__(256) cvt_w_k(const int* __restrict__ w,
                                               unsigned char* __restrict__ wq, int n16) {
    const int stride = gridDim.x * blockDim.x;
    for (int i = blockIdx.x * blockDim.x + threadIdx.x; i < n16; i += stride) {
        const i32x4* p = (const i32x4*)w + (size_t)i * 4;
        i32x4 a = p[0], b = p[1], c = p[2], d = p[3];
        u32x4 o;
        o[0] = pack4(a[0], a[1], a[2], a[3]);
        o[1] = pack4(b[0], b[1], b[2], b[3]);
        o[2] = pack4(c[0], c[1], c[2], c[3]);
        o[3] = pack4(d[0], d[1], d[2], d[3]);
        *((u32x4*)wq + i) = o;
    }
}

// ---------- main GEMM: int8 x int8 -> i32, fp32 epilogue ----------
// Occupancy-first variant: block 128x256, wave tile 64x64 (acc[4][4]=64 regs),
// total regs/wave <= 128 -> 16 waves/CU = 2 blocks co-resident. Block 0's MFMA
// overlaps block 1's LDS/stage. 2 slots x 24KB; chunk-XOR swizzle (0-conflict,
// proven r3..r9). Ledger per body: READS(tk); LGKM0; BAR; STAGE(tk+2);
// MFMA(tk); VM(3) [tile tk+1 landed]; BAR. K-loop fully unrolled.

__global__ void __launch_bounds__(512, 4)
gemm_i8(const unsigned char* __restrict__ Aq, const unsigned char* __restrict__ Bq,
        const float* __restrict__ sx, const float* __restrict__ sw,
        const float* __restrict__ bias, float* __restrict__ C) {
    extern __shared__ __align__(16) char ldsb[];

    // XCD-bijective swizzle (2048 blocks % 8 == 0)
    const int bid = blockIdx.x;
    const int swz = (bid & 7) * 256 + (bid >> 3);
    const int rowBase = (swz >> 5) * 128;   // 64 row-blocks
    const int colBase = (swz & 31) * 256;   // 32 col-blocks

    const int t = threadIdx.x;       // 0..511
    const int l = t & 63;
    const int w = t >> 6;
    const int wm = w >> 2;           // 0..1  (64-row half)
    const int wn = w & 3;            // 0..3  (64-col quarter)
    const int fr = l & 15;
    const int s4 = l >> 4;           // k-group (16 int8 = 16 B)

    // staging: thread t -> row t>>2 (0..127), phys chunk t&3, pre-swizzled src
    const int sr = t >> 2;
    const int sk = (((t & 3) ^ ((sr >> 1) & 3)) * 16);
    const unsigned char* gA0 = Aq + (size_t)(rowBase + sr) * K_DIM + sk;         // A rows 0..127
    const unsigned char* gB0 = Bq + (size_t)(colBase + sr) * K_DIM + sk;         // B rows 0..127
    const unsigned char* gB1 = Bq + (size_t)(colBase + 128 + sr) * K_DIM + sk;   // B rows 128..255

#define STAGE(tk) do { \
        char* _b = ldsb + ((tk) & 1) * SLOT_BYTES; \
        const int _k = (tk) * BK; \
        gload16(gA0 + _k, _b + t * 16); \
        gload16(gB0 + _k, _b + 8192 + t * 16); \
        gload16(gB1 + _k, _b + 16384 + t * 16); \
    } while (0)

    // fragment read offsets (row-terms are multiples of 8 -> key is (fr>>1)&3)
    const int pc = ((s4 ^ ((fr >> 1) & 3)) * 16);
    int aoff[4], boff[4];
#pragma unroll
    for (int mi = 0; mi < 4; ++mi)
        aoff[mi] = (wm * 64 + mi * 16 + fr) * 64 + pc;
#pragma unroll
    for (int ni = 0; ni < 4; ++ni)
        boff[ni] = 8192 + (wn * 64 + ni * 16 + fr) * 64 + pc;

    i32x4 acc[4][4] = {};
    i32x4 af[4], bf[4];

#define SB    __builtin_amdgcn_sched_barrier(0)
#define BAR   __builtin_amdgcn_s_barrier()
#define P1    __builtin_amdgcn_s_setprio(1)
#define P0    __builtin_amdgcn_s_setprio(0)
#define LGKM0 asm volatile("s_waitcnt lgkmcnt(0)" ::: "memory")
#define VM3   asm volatile("s_waitcnt vmcnt(3)" ::: "memory")
#define VM0   asm volatile("s_waitcnt vmcnt(0)" ::: "memory")

#define READS(tk) do { \
        const char* _s = ldsb + ((tk) & 1) * SLOT_BYTES; \
        _Pragma("unroll") \
        for (int mi = 0; mi < 4; ++mi) af[mi] = *(const i32x4*)(_s + aoff[mi]); \
        _Pragma("unroll") \
        for (int ni = 0; ni < 4; ++ni) bf[ni] = *(const i32x4*)(_s + boff[ni]); \
    } while (0)

#define MFMA16 do { P1; \
        _Pragma("unroll") \
        for (int mi = 0; mi < 4; ++mi) \
            _Pragma("unroll") \
            for (int ni = 0; ni < 4; ++ni) \
                acc[mi][ni] = __builtin_amdgcn_mfma_i32_16x16x64_i8( \
                    af[mi], bf[ni], acc[mi][ni], 0, 0, 0); \
        P0; } while (0)

    // prologue: 2 tiles in flight; VM(3) completes tile 0 (6 -> 3 outstanding)
    STAGE(0); STAGE(1);
    VM3; SB; BAR; SB;

    // bodies 0..29 (fully unrolled: immediates for k and slot offsets)
#pragma unroll
    for (int tk = 0; tk < NT - 2; ++tk) {
        READS(tk);                 // 8 ds_read_b128 from slot tk&1
        LGKM0; SB; BAR; SB;        // all waves' reads done -> slot tk&1 free
        STAGE(tk + 2);             // overwrite slot tk&1 with tile tk+2
        MFMA16;                    // compute tile tk (regs); overlaps loads
        VM3; SB; BAR; SB;          // tile tk+1 landed + published
    }
    // body 30: no stage; VM0 forces tile 31
    READS(NT - 2);
    LGKM0; SB; BAR; SB;
    MFMA16;
    VM0; SB; BAR; SB;
    // body 31: final tile
    READS(NT - 1);
    LGKM0; SB;
    MFMA16;

#undef MFMA16
#undef READS
#undef STAGE

    // epilogue: C/D layout col=lane&15, row=(lane>>4)*4+reg (dtype-independent)
    // out = acc_i32 * sx[row] * sw[col] + bias[col]   (fp32, exact dequant)
#pragma unroll
    for (int ni = 0; ni < 4; ++ni) {
        const int col = colBase + wn * 64 + ni * 16 + fr;
        const float swc = sw[col];
        const float bz = bias[col];
#pragma unroll
        for (int mi = 0; mi < 4; ++mi) {
            const int rb = rowBase + wm * 64 + mi * 16 + s4 * 4;
            i32x4 a = acc[mi][ni];
#pragma unroll
            for (int r = 0; r < 4; ++r)
                C[(size_t)(rb + r) * N_DIM + col] =
                    (float)a[r] * (sx[rb + r] * swc) + bz;
        }
    }
}

// ---------- correctness fallback if workspace too small (should not trigger) ----------

typedef int i32x4_t __attribute__((ext_vector_type(4)));
__global__ void __launch_bounds__(256) naive_k(const float* __restrict__ x,
                                               const int* __restrict__ w,
                                               const float* __restrict__ scale,
                                               const float* __restrict__ bias,
                                               float* __restrict__ out) {
    __shared__ float xs[K_DIM];
    const int m = blockIdx.x >> 5;
    const int n = ((blockIdx.x & 31) << 8) + threadIdx.x;
    for (int i = threadIdx.x; i < K_DIM; i += 256) xs[i] = x[(size_t)m * K_DIM + i];
    __syncthreads();
    const int* wr = w + (size_t)n * K_DIM;
    float acc = 0.f;
    for (int k = 0; k < K_DIM; k += 4) {
        i32x4_t v = *(const i32x4_t*)(wr + k);
        acc += xs[k]     * (float)v[0];
        acc += xs[k + 1] * (float)v[1];
        acc += xs[k + 2] * (float)v[2];
        acc += xs[k + 3] * (float)v[3];
    }
    out[(size_t)m * N_DIM + n] = acc * scale[n] + bias[n];
}

// ---------- launch ----------

extern "C" void kernel_launch(void* const* d_in, const int* in_sizes, int n_in,
                              void* d_out, int out_size, void* d_ws, size_t ws_size,
                              hipStream_t stream) {
    const float* x     = (const float*)d_in[0];
    const int*   w8    = (const int*)d_in[1];   // int8 values stored as int32
    const float* sw    = (const float*)d_in[2];
    const float* bias  = (const float*)d_in[3];
    float*       out   = (float*)d_out;

    const size_t xq_bytes = (size_t)M_DIM * K_DIM;          // 16 MB
    const size_t wq_bytes = (size_t)N_DIM * K_DIM;          // 16 MB
    const size_t need = xq_bytes + wq_bytes + (size_t)M_DIM * sizeof(float);
    if (ws_size >= need) {
        unsigned char* xq = (unsigned char*)d_ws;
        unsigned char* wq = xq + xq_bytes;
        float* sx = (float*)(wq + wq_bytes);
        hipFuncSetAttribute((const void*)gemm_i8,
                            hipFuncAttributeMaxDynamicSharedMemorySize, 2 * SLOT_BYTES);
        quant_x_k<<<M_DIM, 256, 0, stream>>>(x, xq, sx);
        cvt_w_k<<<2048, 256, 0, stream>>>(w8, wq, N_DIM * K_DIM / 16);
        gemm_i8<<<dim3((M_DIM / 128) * (N_DIM / 256)), 512, 2 * SLOT_BYTES, stream>>>(
            xq, wq, sx, sw, bias, out);
    } else {
        naive_k<<<(M_DIM * (N_DIM / 256)), 256, 0, stream>>>(x, w8, sw, bias, out);
    }
}

// Round 11
// 235.906 us; speedup vs baseline: 1.0480x; 1.0388x over previous
//
#include <hip/hip_runtime.h>
#include <hip/hip_bf16.h>

#define M_DIM 8192   // 4 * 2048 rows of x
#define N_DIM 8192   // out_features
#define K_DIM 2048   // in_features (= bytes per int8 row)

#define BK 64                 // int8 elems per K-tile
#define NT (K_DIM / BK)       // 32 K-tiles
#define SLOT_BYTES 32768      // A[256][64B] 16KB + B[256][64B] 16KB

typedef float f32x4 __attribute__((ext_vector_type(4)));
typedef int   i32x4 __attribute__((ext_vector_type(4)));
typedef unsigned int u32;
typedef u32 u32x2 __attribute__((ext_vector_type(2)));
typedef u32 u32x4 __attribute__((ext_vector_type(4)));

// ---------- helpers ----------

__device__ __forceinline__ void gload16(const unsigned char* g, char* l) {
    __builtin_amdgcn_global_load_lds(
        (const __attribute__((address_space(1))) u32*)g,
        (__attribute__((address_space(3))) u32*)l, 16, 0, 0);
}

__device__ __forceinline__ u32 pack4(int a, int b, int c, int d) {
    return (u32)(a & 255) | ((u32)(b & 255) << 8) |
           ((u32)(c & 255) << 16) | ((u32)(d & 255) << 24);
}

// ---------- prepass: per-row symmetric int8 quantization of x ----------

__global__ void __launch_bounds__(256) quant_x_k(const float* __restrict__ x,
                                                 unsigned char* __restrict__ xq,
                                                 float* __restrict__ sx) {
    const int row = blockIdx.x;           // 8192 rows
    const int t = threadIdx.x;            // 256 thr, 8 elems each
    const float* xr = x + (size_t)row * K_DIM;
    f32x4 v0 = *((const f32x4*)xr + t * 2);
    f32x4 v1 = *((const f32x4*)xr + t * 2 + 1);
    float m = fabsf(v0[0]);
    m = fmaxf(m, fabsf(v0[1])); m = fmaxf(m, fabsf(v0[2])); m = fmaxf(m, fabsf(v0[3]));
    m = fmaxf(m, fabsf(v1[0])); m = fmaxf(m, fabsf(v1[1]));
    m = fmaxf(m, fabsf(v1[2])); m = fmaxf(m, fabsf(v1[3]));
#pragma unroll
    for (int off = 32; off >= 1; off >>= 1)
        m = fmaxf(m, __shfl_xor(m, off, 64));
    __shared__ float wmax[4];
    if ((t & 63) == 0) wmax[t >> 6] = m;
    __syncthreads();
    m = fmaxf(fmaxf(wmax[0], wmax[1]), fmaxf(wmax[2], wmax[3]));
    m = fmaxf(m, 1e-20f);
    const float rs = 127.0f / m;
    const int q0 = (int)rintf(v0[0] * rs), q1 = (int)rintf(v0[1] * rs);
    const int q2 = (int)rintf(v0[2] * rs), q3 = (int)rintf(v0[3] * rs);
    const int q4 = (int)rintf(v1[0] * rs), q5 = (int)rintf(v1[1] * rs);
    const int q6 = (int)rintf(v1[2] * rs), q7 = (int)rintf(v1[3] * rs);
    u32x2 o;
    o[0] = pack4(q0, q1, q2, q3);
    o[1] = pack4(q4, q5, q6, q7);
    *((u32x2*)(xq + (size_t)row * K_DIM) + t) = o;
    if (t == 0) sx[row] = m / 127.0f;
}

// ---------- prepass: int32 (harness int8-as-int32) -> packed int8 ----------

__global__ void __launch_bounds__(256) cvt_w_k(const int* __restrict__ w,
                                               unsigned char* __restrict__ wq, int n16) {
    const int stride = gridDim.x * blockDim.x;
    for (int i = blockIdx.x * blockDim.x + threadIdx.x; i < n16; i += stride) {
        const i32x4* p = (const i32x4*)w + (size_t)i * 4;
        i32x4 a = p[0], b = p[1], c = p[2], d = p[3];
        u32x4 o;
        o[0] = pack4(a[0], a[1], a[2], a[3]);
        o[1] = pack4(b[0], b[1], b[2], b[3]);
        o[2] = pack4(c[0], c[1], c[2], c[3]);
        o[3] = pack4(d[0], d[1], d[2], d[3]);
        *((u32x4*)wq + i) = o;
    }
}

// ---------- main GEMM: int8 x int8 -> i32, fp32 epilogue ----------
// r7's proven 256x256/4-slot/0-conflict skeleton + REGISTER-LEVEL SOFTWARE
// PIPELINE: body t issues READS(t) into reg set (t&1), then runs MFMA of tile
// t-1 from set ((t-1)&1) while those reads are in flight; LGKM0 at body end
// (after the MFMA has covered the read latency). Ledger: steady outstanding
// {tile t+1}=4; +STAGE(t+2)=8; VM(4) forces tile t+1; BAR publishes it; slot
// overwrite distance = 2 bodies + 2 barriers.

__global__ void __launch_bounds__(512, 2)
gemm_i8(const unsigned char* __restrict__ Aq, const unsigned char* __restrict__ Bq,
        const float* __restrict__ sx, const float* __restrict__ sw,
        const float* __restrict__ bias, float* __restrict__ C) {
    extern __shared__ __align__(16) char ldsb[];

    // XCD-bijective swizzle (1024 blocks % 8 == 0)
    const int bid = blockIdx.x;
    const int swz = (bid & 7) * 128 + (bid >> 3);
    const int rowBase = (swz >> 5) * 256;
    const int colBase = (swz & 31) * 256;

    const int t = threadIdx.x;       // 0..511
    const int l = t & 63;
    const int w = t >> 6;
    const int wm = w >> 2;           // 0..1  (128-row half)
    const int wn = w & 3;            // 0..3  (64-col quarter)
    const int fr = l & 15;
    const int s4 = l >> 4;           // k-group (16 int8 = 16 B)

    // staging: thread t -> row t>>2 (0..127) of each half, phys chunk t&3;
    // source k-offset pre-swizzled: logical chunk = phys ^ ((row>>1)&3)
    const int sr = t >> 2;
    const int sk = (((t & 3) ^ ((sr >> 1) & 3)) * 16);
    const unsigned char* gA0 = Aq + (size_t)(rowBase + sr) * K_DIM + sk;
    const unsigned char* gA1 = Aq + (size_t)(rowBase + 128 + sr) * K_DIM + sk;
    const unsigned char* gB0 = Bq + (size_t)(colBase + sr) * K_DIM + sk;
    const unsigned char* gB1 = Bq + (size_t)(colBase + 128 + sr) * K_DIM + sk;

#define STAGE(tk) do { \
        char* _b = ldsb + ((tk) & 3) * SLOT_BYTES; \
        const int _k = (tk) * BK; \
        gload16(gA0 + _k, _b + t * 16); \
        gload16(gA1 + _k, _b + 8192 + t * 16); \
        gload16(gB0 + _k, _b + 16384 + t * 16); \
        gload16(gB1 + _k, _b + 24576 + t * 16); \
    } while (0)

    // fragment read offsets: key (row>>1)&3 == (fr>>1)&3 for all frag rows
    const int pc = ((s4 ^ ((fr >> 1) & 3)) * 16);
    int aoff[8], boff[4];
#pragma unroll
    for (int mi = 0; mi < 8; ++mi)
        aoff[mi] = (wm * 128 + mi * 16 + fr) * 64 + pc;
#pragma unroll
    for (int ni = 0; ni < 4; ++ni)
        boff[ni] = 16384 + (wn * 64 + ni * 16 + fr) * 64 + pc;

    i32x4 acc[8][4] = {};
    i32x4 af0[8], bf0[4], af1[8], bf1[4];   // ping-pong fragment sets

#define SB    __builtin_amdgcn_sched_barrier(0)
#define BAR   __builtin_amdgcn_s_barrier()
#define P1    __builtin_amdgcn_s_setprio(1)
#define P0    __builtin_amdgcn_s_setprio(0)
#define LGKM0 asm volatile("s_waitcnt lgkmcnt(0)" ::: "memory")
#define VM4   asm volatile("s_waitcnt vmcnt(4)" ::: "memory")
#define VM0   asm volatile("s_waitcnt vmcnt(0)" ::: "memory")

#define READS(T, AF, BF) do { \
        const char* _s = ldsb + ((T) & 3) * SLOT_BYTES; \
        _Pragma("unroll") \
        for (int mi = 0; mi < 8; ++mi) AF[mi] = *(const i32x4*)(_s + aoff[mi]); \
        _Pragma("unroll") \
        for (int ni = 0; ni < 4; ++ni) BF[ni] = *(const i32x4*)(_s + boff[ni]); \
    } while (0)

#define MFMA32(AF, BF) do { P1; \
        _Pragma("unroll") \
        for (int mi = 0; mi < 8; ++mi) \
            _Pragma("unroll") \
            for (int ni = 0; ni < 4; ++ni) \
                acc[mi][ni] = __builtin_amdgcn_mfma_i32_16x16x64_i8( \
                    AF[mi], BF[ni], acc[mi][ni], 0, 0, 0); \
        P0; } while (0)

    // BODY(T): reads(T) -> next set, stage(T+2), MFMA(T-1) from current set
    // (overlaps the in-flight reads), then VM / LGKM0 / BAR.
#define BODY(T, AC, BC, AN, BN, DOSTAGE, VMW) do { \
        READS(T, AN, BN); \
        if (DOSTAGE) STAGE((T) + 2); \
        SB; \
        MFMA32(AC, BC); \
        VMW; LGKM0; SB; BAR; SB; \
    } while (0)

    // prologue: 3 tiles staged (12 loads); VM(4) forces tiles 0,1; reads(0)
    STAGE(0); STAGE(1); STAGE(2);
    VM4; SB; BAR; SB;
    READS(0, af0, bf0);
    LGKM0; SB;

    // bodies 1..28 (pairs): body T computes tile T-1, reads tile T, stages T+2
#pragma unroll
    for (int tt = 1; tt <= 27; tt += 2) {
        BODY(tt,     af0, bf0, af1, bf1, true, VM4);
        BODY(tt + 1, af1, bf1, af0, bf0, true, VM4);
    }
    BODY(29, af0, bf0, af1, bf1, true,  VM4);   // stages tile 31, forces 30
    BODY(30, af1, bf1, af0, bf0, false, VM0);   // forces tile 31
    // body 31: reads(31), MFMA(30), then final MFMA(31)
    READS(31, af1, bf1);
    SB;
    MFMA32(af0, bf0);
    LGKM0; SB;
    MFMA32(af1, bf1);

#undef BODY
#undef MFMA32
#undef READS
#undef STAGE

    // epilogue: C/D layout col=lane&15, row=(lane>>4)*4+reg (dtype-independent)
    // out = acc_i32 * sx[row] * sw[col] + bias[col]   (fp32, exact dequant)
#pragma unroll
    for (int ni = 0; ni < 4; ++ni) {
        const int col = colBase + wn * 64 + ni * 16 + fr;
        const float swc = sw[col];
        const float bz = bias[col];
#pragma unroll
        for (int mi = 0; mi < 8; ++mi) {
            const int rb = rowBase + wm * 128 + mi * 16 + s4 * 4;
            i32x4 a = acc[mi][ni];
#pragma unroll
            for (int r = 0; r < 4; ++r)
                C[(size_t)(rb + r) * N_DIM + col] =
                    (float)a[r] * (sx[rb + r] * swc) + bz;
        }
    }
}

// ---------- correctness fallback if workspace too small (should not trigger) ----------

typedef int i32x4_t __attribute__((ext_vector_type(4)));
__global__ void __launch_bounds__(256) naive_k(const float* __restrict__ x,
                                               const int* __restrict__ w,
                                               const float* __restrict__ scale,
                                               const float* __restrict__ bias,
                                               float* __restrict__ out) {
    __shared__ float xs[K_DIM];
    const int m = blockIdx.x >> 5;
    const int n = ((blockIdx.x & 31) << 8) + threadIdx.x;
    for (int i = threadIdx.x; i < K_DIM; i += 256) xs[i] = x[(size_t)m * K_DIM + i];
    __syncthreads();
    const int* wr = w + (size_t)n * K_DIM;
    float acc = 0.f;
    for (int k = 0; k < K_DIM; k += 4) {
        i32x4_t v = *(const i32x4_t*)(wr + k);
        acc += xs[k]     * (float)v[0];
        acc += xs[k + 1] * (float)v[1];
        acc += xs[k + 2] * (float)v[2];
        acc += xs[k + 3] * (float)v[3];
    }
    out[(size_t)m * N_DIM + n] = acc * scale[n] + bias[n];
}

// ---------- launch ----------

extern "C" void kernel_launch(void* const* d_in, const int* in_sizes, int n_in,
                              void* d_out, int out_size, void* d_ws, size_t ws_size,
                              hipStream_t stream) {
    const float* x     = (const float*)d_in[0];
    const int*   w8    = (const int*)d_in[1];   // int8 values stored as int32
    const float* sw    = (const float*)d_in[2];
    const float* bias  = (const float*)d_in[3];
    float*       out   = (float*)d_out;

    const size_t xq_bytes = (size_t)M_DIM * K_DIM;          // 16 MB
    const size_t wq_bytes = (size_t)N_DIM * K_DIM;          // 16 MB
    const size_t need = xq_bytes + wq_bytes + (size_t)M_DIM * sizeof(float);
    if (ws_size >= need) {
        unsigned char* xq = (unsigned char*)d_ws;
        unsigned char* wq = xq + xq_bytes;
        float* sx = (float*)(wq + wq_bytes);
        hipFuncSetAttribute((const void*)gemm_i8,
                            hipFuncAttributeMaxDynamicSharedMemorySize, 131072);
        quant_x_k<<<M_DIM, 256, 0, stream>>>(x, xq, sx);
        cvt_w_k<<<2048, 256, 0, stream>>>(w8, wq, N_DIM * K_DIM / 16);
        gemm_i8<<<dim3((M_DIM / 256) * (N_DIM / 256)), 512, 131072, stream>>>(
            xq, wq, sx, sw, bias, out);
    } else {
        naive_k<<<(M_DIM * (N_DIM / 256)), 256, 0, stream>>>(x, w8, sw, bias, out);
    }
}